// Round 3
// baseline (1260.153 us; speedup 1.0000x reference)
//
#include <hip/hip_runtime.h>

// GRU stack, hidden_size=1, 6 layers, B=4096, T=2048, D=8.
// One 8-lane group per batch element: lanes 0..5 = layers (skewed pipeline),
// lanes 6..7 idle. Layer l at iteration i handles t = i - l; previous layer's
// h arrives via DPP row_shr:1 (lanes 0,16,32,48 cross rows but are all l==0,
// which ignore the neighbor).
//
// x staging: plain-HIP reg-staged LDS double buffer (NO inline asm, no
// global_load_lds -- round 2 showed those defeat the compiler's scheduler).
// Per 16-step chunk (4KB): each lane issues 4 global_load_dwordx4 one full
// chunk ahead (T14 issue-early/write-late), ds_write_b128 after the barrier.
// Per-step x: 2 x ds_read_b128, same address across the 8-lane group
// (broadcast, conflict-free), hoistable by the compiler.
//
// Gate math in exp2 form, constants pre-folded:
//   sigmoid(p) = rcp(1 + exp2(c1*p)),  c1 = -log2(e)
//   tanh(y)    = 2*rcp(1 + exp2(c2*y)) - 1,  c2 = -2*log2(e)

#define T_LEN 2048
#define T8    (T_LEN * 8)

__device__ __forceinline__ float dpp_shr1(float v) {
    int i = __builtin_bit_cast(int, v);
    int r = __builtin_amdgcn_update_dpp(0, i, 0x111 /*row_shr:1*/, 0xF, 0xF, true);
    return __builtin_bit_cast(float, r);
}

__launch_bounds__(64, 1)
__global__ void gru_scan(const float* __restrict__ x,
                         const float* __restrict__ Wih0,   // [3][8]
                         const float* __restrict__ Wrest,  // [5][3]
                         const float* __restrict__ Whh,    // [6][3]
                         const float* __restrict__ bih,    // [6][3]
                         const float* __restrict__ bhh,    // [6][3]
                         float* __restrict__ out)          // [B]
{
    __shared__ float lds[2048];          // 2 buffers x 1024 floats (4KB each)

    const int lane = threadIdx.x;        // 0..63, block = 1 wave
    const int l    = lane & 7;           // 0..5 layers, 6..7 idle
    const int g    = lane >> 3;          // group (batch) within wave
    const int b    = blockIdx.x * 8 + g;

    const float c1 = -1.44269504088896340736f;   // -log2(e)
    const float c2 = 2.0f * c1;

    const int  lidx = l < 6 ? l : 5;
    const bool lz   = (l == 0);
    const float m1  = lz ? 0.0f : 1.0f;  // zero the nbr weight on layer 0

    const float whpr = c1 * Whh[lidx * 3 + 0];
    const float whpz = c1 * Whh[lidx * 3 + 1];
    const float whpn = c2 * Whh[lidx * 3 + 2];
    const float bhpn = c2 * bhh[lidx * 3 + 2];

    const int ir = lidx >= 1 ? lidx - 1 : 0;
    const float W1r = m1 * c1 * Wrest[ir * 3 + 0];
    const float W1z = m1 * c1 * Wrest[ir * 3 + 1];
    const float W1n = m1 * c2 * Wrest[ir * 3 + 2];
    const float B1r = c1 * (bih[lidx * 3 + 0] + bhh[lidx * 3 + 0]);
    const float B1z = c1 * (bih[lidx * 3 + 1] + bhh[lidx * 3 + 1]);
    const float B1n = c2 *  bih[lidx * 3 + 2];

    // layer-0 projection weights, pre-scaled (uniform)
    float wr[8], wz[8], wn[8];
    #pragma unroll
    for (int d = 0; d < 8; ++d) {
        wr[d] = c1 * Wih0[d];
        wz[d] = c1 * Wih0[8 + d];
        wn[d] = c2 * Wih0[16 + d];
    }

    // ---- staging (lane covers float4-slots q = l + 8r of its own group) ----
    const float* xg = x + (size_t)b * T8;
    float4 st[4];

    auto stage_load = [&](int c) {
        if (c < 128) {
            const float4* p = reinterpret_cast<const float4*>(xg + (size_t)c * 128) + l;
            #pragma unroll
            for (int r = 0; r < 4; ++r) st[r] = p[r * 8];
        }
    };
    auto stage_write = [&](int c) {
        if (c < 128) {
            float* d = &lds[(c & 1) << 10];
            #pragma unroll
            for (int r = 0; r < 4; ++r) {
                const int q    = l + 8 * r;
                const int s    = q >> 1;
                const int half = q & 1;
                *reinterpret_cast<float4*>(&d[s * 64 + g * 8 + half * 4]) = st[r];
            }
        }
    };

    float h = 0.0f;

    auto step = [&](int i, float4 xa, float4 xb, bool guard) {
        const float nbr = dpp_shr1(h);   // prev layer's h (post step i-1)

        // layer-0 projection (all lanes compute; only l==0 consumes)
        float pr = B1r, pz = B1z, pn = B1n;
        pr = fmaf(xa.x, wr[0], pr); pr = fmaf(xa.y, wr[1], pr);
        pr = fmaf(xa.z, wr[2], pr); pr = fmaf(xa.w, wr[3], pr);
        pr = fmaf(xb.x, wr[4], pr); pr = fmaf(xb.y, wr[5], pr);
        pr = fmaf(xb.z, wr[6], pr); pr = fmaf(xb.w, wr[7], pr);
        pz = fmaf(xa.x, wz[0], pz); pz = fmaf(xa.y, wz[1], pz);
        pz = fmaf(xa.z, wz[2], pz); pz = fmaf(xa.w, wz[3], pz);
        pz = fmaf(xb.x, wz[4], pz); pz = fmaf(xb.y, wz[5], pz);
        pz = fmaf(xb.z, wz[6], pz); pz = fmaf(xb.w, wz[7], pz);
        pn = fmaf(xa.x, wn[0], pn); pn = fmaf(xa.y, wn[1], pn);
        pn = fmaf(xa.z, wn[2], pn); pn = fmaf(xa.w, wn[3], pn);
        pn = fmaf(xb.x, wn[4], pn); pn = fmaf(xb.y, wn[5], pn);
        pn = fmaf(xb.z, wn[6], pn); pn = fmaf(xb.w, wn[7], pn);

        // bias/projection base, selected OFF the h-chain
        const float br = lz ? pr : B1r;
        const float bz = lz ? pz : B1z;
        const float bn = lz ? pn : B1n;

        const float ar = fmaf(whpr, h, fmaf(W1r, nbr, br));
        const float er = __builtin_amdgcn_exp2f(ar);
        const float r  = __builtin_amdgcn_rcpf(1.0f + er);
        const float az = fmaf(whpz, h, fmaf(W1z, nbr, bz));
        const float ez = __builtin_amdgcn_exp2f(az);
        const float z  = __builtin_amdgcn_rcpf(1.0f + ez);
        const float xnp = fmaf(W1n, nbr, bn);
        const float tn  = fmaf(whpn, h, bhpn);
        const float en  = __builtin_amdgcn_exp2f(fmaf(r, tn, xnp));
        const float dd  = __builtin_amdgcn_rcpf(1.0f + en);

        const float omz  = 1.0f - z;
        const float omz2 = omz + omz;
        const float bse  = fmaf(z, h, -omz);
        const float hn   = fmaf(omz2, dd, bse);   // (1-z)*tanh + z*h

        if (guard) {
            h = ((unsigned)(i - l) < (unsigned)T_LEN) ? hn : h;
        } else {
            h = hn;
        }
    };

    auto run_chunk = [&](int c, bool guard) {
        const float* bufp = &lds[(c & 1) << 10];
        #pragma unroll
        for (int s = 0; s < 16; ++s) {
            const float4 xa = *reinterpret_cast<const float4*>(&bufp[s * 64 + g * 8]);
            const float4 xb = *reinterpret_cast<const float4*>(&bufp[s * 64 + g * 8 + 4]);
            step(c * 16 + s, xa, xb, guard);
        }
    };

    // prologue: buf0 staged, chunk-1 loads in flight
    stage_load(0);
    stage_write(0);
    stage_load(1);
    __syncthreads();

    run_chunk(0, true);          // guarded (t<0 lanes freeze at 0)
    stage_write(1);
    stage_load(2);
    __syncthreads();

    #pragma unroll 1
    for (int c = 1; c < 128; ++c) {
        run_chunk(c, false);
        stage_write(c + 1);      // skipped when c+1 >= 128
        stage_load(c + 2);
        __syncthreads();
    }

    // tail: 5 guarded steps, no x (layer 0 frozen; others finish t up to 2047)
    const float4 zf = make_float4(0.f, 0.f, 0.f, 0.f);
    #pragma unroll
    for (int i = T_LEN; i < T_LEN + 5; ++i) step(i, zf, zf, true);

    if (l == 5) out[b] = h;      // layer-5 h frozen at t = T-1
}

extern "C" void kernel_launch(void* const* d_in, const int* in_sizes, int n_in,
                              void* d_out, int out_size, void* d_ws, size_t ws_size,
                              hipStream_t stream) {
    const float* x     = (const float*)d_in[0];
    const float* Wih0  = (const float*)d_in[1];
    const float* Wrest = (const float*)d_in[2];
    const float* Whh   = (const float*)d_in[3];
    const float* bih   = (const float*)d_in[4];
    const float* bhh   = (const float*)d_in[5];
    float* out = (float*)d_out;

    gru_scan<<<512, 64, 0, stream>>>(x, Wih0, Wrest, Whh, bih, bhh, out);
}

// Round 4
// 262.391 us; speedup vs baseline: 4.8026x; 4.8026x over previous
//
#include <hip/hip_runtime.h>

// GRU stack, hidden_size=1, 6 layers, B=4096, T=2048, D=8.
// One 8-lane group per batch element: lanes 0..5 = layers (skewed pipeline),
// lanes 6..7 idle. Layer l at iteration i handles t = i - l; previous layer's
// h arrives via DPP row_shr:1 (the lanes where row_shr:1 crosses a row
// boundary -- 0,16,32,48 -- are all l==0, which ignore the neighbor).
//
// x prefetch: register double buffer, 8-timestep chunks (16 float4 each).
// amdgpu_waves_per_eu(1,1) pins the occupancy target to 1 wave/EU (we only
// have 512 waves for 1024 SIMDs anyway), raising the VGPR budget to 512 so
// the allocator keeps XA/XB (128 VGPRs) resident instead of sinking the
// loads to their uses (round 1's 350cy/step stall, VGPR_Count=96).
// NO inline asm, NO LDS: rounds 2/3 showed both trigger scratch spills here.
//
// Gate math in exp2 form, constants pre-folded:
//   sigmoid(p) = rcp(1 + exp2(c1*p)),  c1 = -log2(e)
//   tanh(y)    = 2*rcp(1 + exp2(c2*y)) - 1,  c2 = -2*log2(e)

#define T_LEN 2048
#define T8    (T_LEN * 8)
#define NCH   256          // 8-step chunks covering i = 0..2047

__device__ __forceinline__ float dpp_shr1(float v) {
    int i = __builtin_bit_cast(int, v);
    int r = __builtin_amdgcn_update_dpp(0, i, 0x111 /*row_shr:1*/, 0xF, 0xF, true);
    return __builtin_bit_cast(float, r);
}

__global__ __launch_bounds__(64)
__attribute__((amdgpu_waves_per_eu(1, 1)))
void gru_scan(const float* __restrict__ x,
              const float* __restrict__ Wih0,   // [3][8]
              const float* __restrict__ Wrest,  // [5][3]
              const float* __restrict__ Whh,    // [6][3]
              const float* __restrict__ bih,    // [6][3]
              const float* __restrict__ bhh,    // [6][3]
              float* __restrict__ out)          // [B]
{
    const int lane = threadIdx.x;        // 0..63, block = 1 wave
    const int l    = lane & 7;           // 0..5 layers, 6..7 idle
    const int g    = lane >> 3;          // group (batch) within wave
    const int b    = blockIdx.x * 8 + g;

    const float c1 = -1.44269504088896340736f;   // -log2(e)
    const float c2 = 2.0f * c1;

    const int  lidx = l < 6 ? l : 5;
    const bool lz   = (l == 0);
    const float m1  = lz ? 0.0f : 1.0f;  // zero the nbr weight on layer 0

    const float whpr = c1 * Whh[lidx * 3 + 0];
    const float whpz = c1 * Whh[lidx * 3 + 1];
    const float whpn = c2 * Whh[lidx * 3 + 2];
    const float bhpn = c2 * bhh[lidx * 3 + 2];

    const int ir = lidx >= 1 ? lidx - 1 : 0;
    const float W1r = m1 * c1 * Wrest[ir * 3 + 0];
    const float W1z = m1 * c1 * Wrest[ir * 3 + 1];
    const float W1n = m1 * c2 * Wrest[ir * 3 + 2];
    const float B1r = c1 * (bih[lidx * 3 + 0] + bhh[lidx * 3 + 0]);
    const float B1z = c1 * (bih[lidx * 3 + 1] + bhh[lidx * 3 + 1]);
    const float B1n = c2 *  bih[lidx * 3 + 2];

    // layer-0 projection weights, pre-scaled (uniform across lanes)
    float wr[8], wz[8], wn[8];
    #pragma unroll
    for (int d = 0; d < 8; ++d) {
        wr[d] = c1 * Wih0[d];
        wz[d] = c1 * Wih0[8 + d];
        wn[d] = c2 * Wih0[16 + d];
    }

    // all lanes of a group load the group's x (same addresses -> coalescer
    // merges to one line; removes divergent exec-mask around the load batch)
    const float* xg = x + (size_t)b * T8;

    float4 XA[16], XB[16];   // two 8-timestep chunks, 64 VGPRs each
    float  h = 0.0f;

    auto loadc = [&](float4 (&X)[16], int c) {
        if (c < NCH) {
            const float4* p = reinterpret_cast<const float4*>(xg) + c * 16;
            #pragma unroll
            for (int j = 0; j < 16; ++j) X[j] = p[j];
        }
    };

    auto step = [&](int i, float4 xa, float4 xb, bool guard) {
        const float nbr = dpp_shr1(h);   // prev layer's h (post step i-1)

        // layer-0 projection (all lanes compute; only l==0 consumes)
        float pr = B1r, pz = B1z, pn = B1n;
        pr = fmaf(xa.x, wr[0], pr); pr = fmaf(xa.y, wr[1], pr);
        pr = fmaf(xa.z, wr[2], pr); pr = fmaf(xa.w, wr[3], pr);
        pr = fmaf(xb.x, wr[4], pr); pr = fmaf(xb.y, wr[5], pr);
        pr = fmaf(xb.z, wr[6], pr); pr = fmaf(xb.w, wr[7], pr);
        pz = fmaf(xa.x, wz[0], pz); pz = fmaf(xa.y, wz[1], pz);
        pz = fmaf(xa.z, wz[2], pz); pz = fmaf(xa.w, wz[3], pz);
        pz = fmaf(xb.x, wz[4], pz); pz = fmaf(xb.y, wz[5], pz);
        pz = fmaf(xb.z, wz[6], pz); pz = fmaf(xb.w, wz[7], pz);
        pn = fmaf(xa.x, wn[0], pn); pn = fmaf(xa.y, wn[1], pn);
        pn = fmaf(xa.z, wn[2], pn); pn = fmaf(xa.w, wn[3], pn);
        pn = fmaf(xb.x, wn[4], pn); pn = fmaf(xb.y, wn[5], pn);
        pn = fmaf(xb.z, wn[6], pn); pn = fmaf(xb.w, wn[7], pn);

        // bias/projection base, selected OFF the h-chain
        const float br = lz ? pr : B1r;
        const float bz = lz ? pz : B1z;
        const float bn = lz ? pn : B1n;

        const float ar = fmaf(whpr, h, fmaf(W1r, nbr, br));
        const float er = __builtin_amdgcn_exp2f(ar);
        const float r  = __builtin_amdgcn_rcpf(1.0f + er);
        const float az = fmaf(whpz, h, fmaf(W1z, nbr, bz));
        const float ez = __builtin_amdgcn_exp2f(az);
        const float z  = __builtin_amdgcn_rcpf(1.0f + ez);
        const float xnp = fmaf(W1n, nbr, bn);
        const float tn  = fmaf(whpn, h, bhpn);
        const float en  = __builtin_amdgcn_exp2f(fmaf(r, tn, xnp));
        const float dd  = __builtin_amdgcn_rcpf(1.0f + en);

        const float omz  = 1.0f - z;
        const float omz2 = omz + omz;
        const float bse  = fmaf(z, h, -omz);
        const float hn   = fmaf(omz2, dd, bse);   // (1-z)*tanh + z*h

        if (guard) {
            h = ((unsigned)(i - l) < (unsigned)T_LEN) ? hn : h;
        } else {
            h = hn;
        }
    };

    auto stepc = [&](const float4 (&X)[16], int c, bool guard) {
        #pragma unroll
        for (int s = 0; s < 8; ++s)
            step(c * 8 + s, X[2 * s], X[2 * s + 1], guard);
    };

    // prologue: two chunks in flight
    loadc(XA, 0);
    loadc(XB, 1);

    // first pair: chunk 0 guarded (lanes with t<0 freeze)
    stepc(XA, 0, true);
    loadc(XA, 2);
    stepc(XB, 1, false);
    loadc(XB, 3);

    #pragma unroll 1
    for (int k = 1; k < 128; ++k) {
        stepc(XA, 2 * k, false);
        loadc(XA, 2 * k + 2);        // no-op once past chunk 255
        stepc(XB, 2 * k + 1, false);
        loadc(XB, 2 * k + 3);
    }

    // tail: 5 guarded steps, x = 0 (layer 0 frozen; layers 1..5 finish)
    const float4 zf = make_float4(0.f, 0.f, 0.f, 0.f);
    #pragma unroll
    for (int i = T_LEN; i < T_LEN + 5; ++i) step(i, zf, zf, true);

    if (l == 5) out[b] = h;          // layer-5 h frozen at t = T-1
}

extern "C" void kernel_launch(void* const* d_in, const int* in_sizes, int n_in,
                              void* d_out, int out_size, void* d_ws, size_t ws_size,
                              hipStream_t stream) {
    const float* x     = (const float*)d_in[0];
    const float* Wih0  = (const float*)d_in[1];
    const float* Wrest = (const float*)d_in[2];
    const float* Whh   = (const float*)d_in[3];
    const float* bih   = (const float*)d_in[4];
    const float* bhh   = (const float*)d_in[5];
    float* out = (float*)d_out;

    gru_scan<<<512, 64, 0, stream>>>(x, Wih0, Wrest, Whh, bih, bhh, out);
}

// Round 6
// 201.686 us; speedup vs baseline: 6.2481x; 1.3010x over previous
//
#include <hip/hip_runtime.h>

// GRU stack, hidden_size=1, 6 layers, B=4096, T=2048, D=8.
// One 8-lane group per batch element: lanes 0..5 = layers (skewed pipeline).
// Layer l at iteration i handles t = i - l; previous layer's h arrives via
// DPP row_shr:1 (row-crossing lanes 0,16,32,48 are all l==0 -> ignore nbr).
//
// Layer-0 input projection computed ONCE per 8-step chunk, distributed
// across the group's 8 lanes (lane j does step j's three 8-wide dots =
// 24 FMA/chunk instead of 24 FMA/step), then broadcast to the group via
// ds_swizzle BitMode src=(lane&0x18)|s -- hand-unrolled via macro because
// the swizzle pattern must be an integer constant expression (round 5's
// compile failure). x per lane is 2 float4 per chunk, so the 4-buffer
// distance-2 register pipeline (load c+3 / prep c+1 / run c) stays resident.
// NO LDS tiles, no inline asm (rounds 2/3 regressions).
//
// Gate math in exp2 form, constants pre-folded:
//   sigmoid(p) = rcp(1 + exp2(c1*p)),  c1 = -log2(e)
//   tanh(y)    = 2*rcp(1 + exp2(c2*y)) - 1,  c2 = -2*log2(e)

#define T_LEN 2048
#define T8    (T_LEN * 8)
#define NCH   256          // 8-step chunks

__device__ __forceinline__ float dpp_shr1(float v) {
    int i = __builtin_bit_cast(int, v);
    int r = __builtin_amdgcn_update_dpp(0, i, 0x111 /*row_shr:1*/, 0xF, 0xF, true);
    return __builtin_bit_cast(float, r);
}

__global__ __launch_bounds__(64)
__attribute__((amdgpu_waves_per_eu(1, 1)))
void gru_scan(const float* __restrict__ x,
              const float* __restrict__ Wih0,   // [3][8]
              const float* __restrict__ Wrest,  // [5][3]
              const float* __restrict__ Whh,    // [6][3]
              const float* __restrict__ bih,    // [6][3]
              const float* __restrict__ bhh,    // [6][3]
              float* __restrict__ out)          // [B]
{
    const int lane = threadIdx.x;        // 0..63, block = 1 wave
    const int l    = lane & 7;           // 0..5 layers; 6,7 proj-only helpers
    const int g    = lane >> 3;          // group (batch) within wave
    const int b    = blockIdx.x * 8 + g;

    const float c1 = -1.44269504088896340736f;   // -log2(e)
    const float c2 = 2.0f * c1;

    const int  lidx = l < 6 ? l : 5;
    const bool lz   = (l == 0);
    const float m1  = lz ? 0.0f : 1.0f;

    const float whpr = c1 * Whh[lidx * 3 + 0];
    const float whpz = c1 * Whh[lidx * 3 + 1];
    const float whpn = c2 * Whh[lidx * 3 + 2];
    const float bhpn = c2 * bhh[lidx * 3 + 2];

    const int ir = lidx >= 1 ? lidx - 1 : 0;
    const float W1r = m1 * c1 * Wrest[ir * 3 + 0];
    const float W1z = m1 * c1 * Wrest[ir * 3 + 1];
    const float W1n = m1 * c2 * Wrest[ir * 3 + 2];
    const float B1r = c1 * (bih[lidx * 3 + 0] + bhh[lidx * 3 + 0]);
    const float B1z = c1 * (bih[lidx * 3 + 1] + bhh[lidx * 3 + 1]);
    const float B1n = c2 *  bih[lidx * 3 + 2];

    // layer-0 constants (uniform across lanes) for the distributed projection
    const float B0r = c1 * (bih[0] + bhh[0]);
    const float B0z = c1 * (bih[1] + bhh[1]);
    const float B0n = c2 *  bih[2];
    float wr[8], wz[8], wn[8];
    #pragma unroll
    for (int d = 0; d < 8; ++d) {
        wr[d] = c1 * Wih0[d];
        wz[d] = c1 * Wih0[8 + d];
        wn[d] = c2 * Wih0[16 + d];
    }

    // lane j of a group loads only step j's 32B of each chunk
    const float4* xp = reinterpret_cast<const float4*>(x + (size_t)b * T8) + (lane & 7) * 2;

    float4 L0[2], L1[2], L2[2], L3[2];       // chunk c -> L[c&3]
    float  Sr0[8], Sz0[8], Sn0[8];           // chunk c -> S[c&1]
    float  Sr1[8], Sz1[8], Sn1[8];
    float  h = 0.0f;

    auto loadL = [&](float4 (&L)[2], int c) {
        const int cc = (c < NCH) ? c : 0;    // clamp: harmless re-read of chunk 0
        const float4* p = xp + (size_t)cc * 16;
        L[0] = p[0];
        L[1] = p[1];
    };

    // distributed projection + group broadcast + base select (all off h-chain)
    auto prep = [&](const float4 (&L)[2],
                    float (&sr)[8], float (&sz)[8], float (&sn)[8]) {
        const float4 a  = L[0];
        const float4 b4 = L[1];
        float pr = B0r, pz = B0z, pn = B0n;
        pr = fmaf(a.x,  wr[0], pr); pr = fmaf(a.y,  wr[1], pr);
        pr = fmaf(a.z,  wr[2], pr); pr = fmaf(a.w,  wr[3], pr);
        pr = fmaf(b4.x, wr[4], pr); pr = fmaf(b4.y, wr[5], pr);
        pr = fmaf(b4.z, wr[6], pr); pr = fmaf(b4.w, wr[7], pr);
        pz = fmaf(a.x,  wz[0], pz); pz = fmaf(a.y,  wz[1], pz);
        pz = fmaf(a.z,  wz[2], pz); pz = fmaf(a.w,  wz[3], pz);
        pz = fmaf(b4.x, wz[4], pz); pz = fmaf(b4.y, wz[5], pz);
        pz = fmaf(b4.z, wz[6], pz); pz = fmaf(b4.w, wz[7], pz);
        pn = fmaf(a.x,  wn[0], pn); pn = fmaf(a.y,  wn[1], pn);
        pn = fmaf(a.z,  wn[2], pn); pn = fmaf(a.w,  wn[3], pn);
        pn = fmaf(b4.x, wn[4], pn); pn = fmaf(b4.y, wn[5], pn);
        pn = fmaf(b4.z, wn[6], pn); pn = fmaf(b4.w, wn[7], pn);

        const int ipr = __builtin_bit_cast(int, pr);
        const int ipz = __builtin_bit_cast(int, pz);
        const int ipn = __builtin_bit_cast(int, pn);

        // BitMode: src_lane = (lane & 0x18) | S -> broadcast step-S projection.
        // Pattern must be an integer constant expression -> macro unroll.
#define BCAST_STEP(S)                                                         \
        {                                                                     \
            const float qr = __builtin_bit_cast(float,                        \
                __builtin_amdgcn_ds_swizzle(ipr, ((S) << 5) | 0x18));         \
            const float qz = __builtin_bit_cast(float,                        \
                __builtin_amdgcn_ds_swizzle(ipz, ((S) << 5) | 0x18));         \
            const float qn = __builtin_bit_cast(float,                        \
                __builtin_amdgcn_ds_swizzle(ipn, ((S) << 5) | 0x18));         \
            sr[S] = lz ? qr : B1r;                                            \
            sz[S] = lz ? qz : B1z;                                            \
            sn[S] = lz ? qn : B1n;                                            \
        }
        BCAST_STEP(0) BCAST_STEP(1) BCAST_STEP(2) BCAST_STEP(3)
        BCAST_STEP(4) BCAST_STEP(5) BCAST_STEP(6) BCAST_STEP(7)
#undef BCAST_STEP
    };

    auto step1 = [&](int i, float br, float bz, float bn, bool guard) {
        const float nbr = dpp_shr1(h);       // prev layer's h

        const float inr = fmaf(W1r, nbr, br);    // W1*==0 on layer 0
        const float inz = fmaf(W1z, nbr, bz);
        const float inn = fmaf(W1n, nbr, bn);

        const float er = __builtin_amdgcn_exp2f(fmaf(whpr, h, inr));
        const float r  = __builtin_amdgcn_rcpf(1.0f + er);
        const float ez = __builtin_amdgcn_exp2f(fmaf(whpz, h, inz));
        const float z  = __builtin_amdgcn_rcpf(1.0f + ez);
        const float tn = fmaf(whpn, h, bhpn);
        const float en = __builtin_amdgcn_exp2f(fmaf(r, tn, inn));
        const float dd = __builtin_amdgcn_rcpf(1.0f + en);

        const float omz  = 1.0f - z;
        const float omz2 = omz + omz;
        const float bse  = fmaf(z, h, -omz);
        const float hn   = fmaf(omz2, dd, bse);  // (1-z)*tanh + z*h

        if (guard) {
            h = ((unsigned)(i - l) < (unsigned)T_LEN) ? hn : h;
        } else {
            h = hn;
        }
    };

    auto runc = [&](const float (&sr)[8], const float (&sz)[8],
                    const float (&sn)[8], int c, bool guard) {
        #pragma unroll
        for (int s = 0; s < 8; ++s)
            step1(c * 8 + s, sr[s], sz[s], sn[s], guard);
    };

    // ---- software pipeline: load(c+3) | prep(c+1) | run(c) ----
    loadL(L0, 0); loadL(L1, 1); loadL(L2, 2);
    prep(L0, Sr0, Sz0, Sn0);

    loadL(L3, 3); prep(L1, Sr1, Sz1, Sn1); runc(Sr0, Sz0, Sn0, 0, true);
    loadL(L0, 4); prep(L2, Sr0, Sz0, Sn0); runc(Sr1, Sz1, Sn1, 1, false);
    loadL(L1, 5); prep(L3, Sr1, Sz1, Sn1); runc(Sr0, Sz0, Sn0, 2, false);
    loadL(L2, 6); prep(L0, Sr0, Sz0, Sn0); runc(Sr1, Sz1, Sn1, 3, false);

    #pragma unroll 1
    for (int q = 1; q < 64; ++q) {
        const int c0 = q * 4;
        loadL(L3, c0 + 3); prep(L1, Sr1, Sz1, Sn1); runc(Sr0, Sz0, Sn0, c0,     false);
        loadL(L0, c0 + 4); prep(L2, Sr0, Sz0, Sn0); runc(Sr1, Sz1, Sn1, c0 + 1, false);
        loadL(L1, c0 + 5); prep(L3, Sr1, Sz1, Sn1); runc(Sr0, Sz0, Sn0, c0 + 2, false);
        loadL(L2, c0 + 6); prep(L0, Sr0, Sz0, Sn0); runc(Sr1, Sz1, Sn1, c0 + 3, false);
    }

    // tail: 5 guarded steps, no x (layer 0 frozen; layers 1..5 finish)
    #pragma unroll
    for (int i = T_LEN; i < T_LEN + 5; ++i) step1(i, B1r, B1z, B1n, true);

    if (l == 5) out[b] = h;          // layer-5 h frozen at t = T-1
}

extern "C" void kernel_launch(void* const* d_in, const int* in_sizes, int n_in,
                              void* d_out, int out_size, void* d_ws, size_t ws_size,
                              hipStream_t stream) {
    const float* x     = (const float*)d_in[0];
    const float* Wih0  = (const float*)d_in[1];
    const float* Wrest = (const float*)d_in[2];
    const float* Whh   = (const float*)d_in[3];
    const float* bih   = (const float*)d_in[4];
    const float* bhh   = (const float*)d_in[5];
    float* out = (float*)d_out;

    gru_scan<<<512, 64, 0, stream>>>(x, Wih0, Wrest, Whh, bih, bhh, out);
}